// Round 6
// baseline (96.926 us; speedup 1.0000x reference)
//
#include <hip/hip_runtime.h>
#include <hip/hip_fp16.h>

#define NN 100000
#define NE 625000
#define ND 128
#define NR 16
#define SLOPE 0.2f
#define PAD 132            // floats per LDS x-row: 128+4 (conflict-free ds_read_b128)
#define CAP 101376         // bucket capacity, multiple of 1024; E[count]=78125, +86 sigma
#define PRE_BLOCKS 1563    // ceil(NN/64)
#define SC_BLOCKS 611      // ceil(NE/1024)

// counters: scur[8] = scatter cursors / final bucket counts; bcur[8] = AB chunk cursors
__global__ void zero_counters(unsigned* __restrict__ c) {
    if (threadIdx.x < 16) c[threadIdx.x] = 0u;
}

// Fused kernel, two independent roles by blockIdx:
//  role A (blocks [0,1563)): precompute planar fp16 table + zero segsum.
//    plane p in [0,16): U_p[n] = dot(a[p][0:128], x[n]); plane 16+p: V_p[n] = dot(a[p][128:256], x[n])
//    4 waves/block, 64 nodes; wave q computes 8 outputs/node; A-rows via wave-uniform scalar loads.
//  role B (blocks [1563, 2174)): bin 1024 edges by (rel & 7) into bucket arrays
//    bs = src | (rel>>3)<<20, bd = dst, beid = edge id. Two-phase LDS rank + one
//    global cursor reservation per bucket per block.
__global__ __launch_bounds__(256) void pre_scatter(
        const float* __restrict__ x, const float* __restrict__ a,
        const int* __restrict__ srcs, const int* __restrict__ dsts,
        const int* __restrict__ etype,
        __half* __restrict__ table, float* __restrict__ segsum,
        unsigned* __restrict__ scur,
        int* __restrict__ bs, int* __restrict__ bd, int* __restrict__ beid) {
    __shared__ float xs[64 * PAD];          // 33,792 B (role B aliases first 64 B)
    int tid = threadIdx.x;
    int b = blockIdx.x;

    if (b < PRE_BLOCKS) {
        // ---------------- role A: precompute ----------------
        int blockBase = b * 64;
#pragma unroll
        for (int i = 0; i < 8; ++i) {
            int f = tid + i * 256;
            int row = f >> 5;
            int col = (f & 31) << 2;
            size_t g = (size_t)blockBase * ND + (size_t)f * 4;
            float4 v = (g < (size_t)NN * ND) ? *(const float4*)&x[g]
                                             : make_float4(0.f, 0.f, 0.f, 0.f);
            *(float4*)&xs[row * PAD + col] = v;
        }
        __syncthreads();

        int q  = __builtin_amdgcn_readfirstlane(tid >> 6);
        int nl = tid & 63;
        int n  = blockBase + nl;
        if (n >= NN) return;
        if (q == 0) segsum[n] = 0.0f;

        const float* arow = a + (size_t)((q & 1) * 8) * 256 + (q >> 1) * 128;
        float acc[8];
#pragma unroll
        for (int j = 0; j < 8; ++j) acc[j] = 0.0f;

        const float* xr = &xs[nl * PAD];
        for (int k = 0; k < ND; k += 4) {
            float4 xv = *(const float4*)&xr[k];
#pragma unroll
            for (int j = 0; j < 8; ++j) {
                float4 av = *(const float4*)&arow[(size_t)j * 256 + k];  // s_load
                acc[j] += av.x * xv.x + av.y * xv.y + av.z * xv.z + av.w * xv.w;
            }
        }
#pragma unroll
        for (int j = 0; j < 8; ++j) {
            int plane = ((q >> 1) << 4) + (q & 1) * 8 + j;   // wave-coalesced 128 B stores
            table[(size_t)plane * NN + n] = __float2half_rn(acc[j]);
        }
    } else {
        // ---------------- role B: bucket scatter ----------------
        unsigned* h     = (unsigned*)xs;      // [8]
        unsigned* hbase = h + 8;              // [8]
        if (tid < 8) h[tid] = 0u;
        __syncthreads();

        int e0 = (b - PRE_BLOCKS) * 1024 + tid * 4;
        bool valid = e0 < NE;                 // NE % 4 == 0: all-or-none per thread
        int4 s4, d4, r4;
        int gb[4]; unsigned rank[4];
        if (valid) {
            s4 = *(const int4*)&srcs[e0];
            d4 = *(const int4*)&dsts[e0];
            r4 = *(const int4*)&etype[e0];
            int rr[4] = {r4.x, r4.y, r4.z, r4.w};
#pragma unroll
            for (int j = 0; j < 4; ++j) {
                gb[j] = rr[j] & 7;
                rank[j] = atomicAdd(&h[gb[j]], 1u);
            }
        }
        __syncthreads();
        if (tid < 8) hbase[tid] = h[tid] ? atomicAdd(&scur[tid], h[tid]) : 0u;
        __syncthreads();
        if (valid) {
            int ss[4] = {s4.x, s4.y, s4.z, s4.w};
            int dd[4] = {d4.x, d4.y, d4.z, d4.w};
            int rr[4] = {r4.x, r4.y, r4.z, r4.w};
#pragma unroll
            for (int j = 0; j < 4; ++j) {
                unsigned pos = (unsigned)gb[j] * CAP + hbase[gb[j]] + rank[j];
                bs[pos]   = ss[j] | ((rr[j] >> 3) << 20);
                bd[pos]   = dd[j];
                beid[pos] = e0 + j;
            }
        }
    }
}

// AB: each block serves ITS OWN XCD's bucket (bucket g == XCC_ID), stealing
// 1024-edge chunks. All table gathers confined to an 800 KB slab -> L2-resident.
// ex overwrites bd in place (sequential); atomic segment-sum into segsum.
__global__ __launch_bounds__(256) void edge_ab(
        const unsigned* __restrict__ scur, unsigned* __restrict__ bcur,
        const int* __restrict__ bs, int* __restrict__ bdx,
        const __half* __restrict__ table, float* __restrict__ segsum) {
    __shared__ unsigned chunk_s;
    int xcd;
    asm volatile("s_getreg_b32 %0, hwreg(HW_REG_XCC_ID)" : "=s"(xcd));
    int g = xcd & 7;
    unsigned count = scur[g];

    for (;;) {
        if (threadIdx.x == 0) chunk_s = atomicAdd(&bcur[g], 1u);
        __syncthreads();
        unsigned chunk = chunk_s;
        __syncthreads();
        if (chunk * 1024u >= count) break;

        unsigned local = chunk * 1024u + threadIdx.x * 4u;
        if (local >= count) continue;
        unsigned i = (unsigned)g * CAP + local;

        if (local + 3u < count) {
            int4 w4 = *(const int4*)&bs[i];
            int4 d4 = *(const int4*)&bdx[i];
            int w[4] = {w4.x, w4.y, w4.z, w4.w};
            int d[4] = {d4.x, d4.y, d4.z, d4.w};
            float ex[4]; int s[4];
#pragma unroll
            for (int j = 0; j < 4; ++j) {
                s[j] = w[j] & 0x1FFFF;
                int r = g | (((w[j] >> 20) & 1) << 3);
                float u = __half2float(table[(unsigned)r * NN + (unsigned)s[j]]);
                float v = __half2float(table[(unsigned)(16 + r) * NN + (unsigned)d[j]]);
                float av = u + v;
                av = (av >= 0.f) ? av : SLOPE * av;
                ex[j] = __expf(av);
            }
            int4 exv = make_int4(__float_as_int(ex[0]), __float_as_int(ex[1]),
                                 __float_as_int(ex[2]), __float_as_int(ex[3]));
            *(int4*)&bdx[i] = exv;
#pragma unroll
            for (int j = 0; j < 4; ++j) atomicAdd(&segsum[s[j]], ex[j]);
        } else {
#pragma unroll
            for (int j = 0; j < 4; ++j) {
                if (local + j < count) {
                    int w = bs[i + j];
                    int d = bdx[i + j];
                    int sj = w & 0x1FFFF;
                    int r = g | (((w >> 20) & 1) << 3);
                    float u = __half2float(table[(unsigned)r * NN + (unsigned)sj]);
                    float v = __half2float(table[(unsigned)(16 + r) * NN + (unsigned)d]);
                    float av = u + v;
                    av = (av >= 0.f) ? av : SLOPE * av;
                    float exj = __expf(av);
                    bdx[i + j] = __float_as_int(exj);
                    atomicAdd(&segsum[sj], exj);
                }
            }
        }
    }
}

// C: walk buckets (static split: bucket = blockIdx&7), alpha = ex / segsum[src],
// scatter to out[orig edge id].
__global__ __launch_bounds__(256) void edge_c(
        const unsigned* __restrict__ scur,
        const int* __restrict__ bs, const int* __restrict__ bdx,
        const int* __restrict__ beid,
        const float* __restrict__ segsum, float* __restrict__ out) {
    int g = blockIdx.x & 7;
    unsigned count = scur[g];
    for (unsigned chunk = (unsigned)(blockIdx.x >> 3); chunk * 1024u < count; chunk += 128u) {
        unsigned local = chunk * 1024u + threadIdx.x * 4u;
        if (local >= count) continue;
        unsigned i = (unsigned)g * CAP + local;
        if (local + 3u < count) {
            int4 w4  = *(const int4*)&bs[i];
            int4 x4  = *(const int4*)&bdx[i];
            int4 id4 = *(const int4*)&beid[i];
            out[id4.x] = __fdividef(__int_as_float(x4.x), segsum[w4.x & 0x1FFFF]);
            out[id4.y] = __fdividef(__int_as_float(x4.y), segsum[w4.y & 0x1FFFF]);
            out[id4.z] = __fdividef(__int_as_float(x4.z), segsum[w4.z & 0x1FFFF]);
            out[id4.w] = __fdividef(__int_as_float(x4.w), segsum[w4.w & 0x1FFFF]);
        } else {
#pragma unroll
            for (int j = 0; j < 4; ++j) {
                if (local + j < count) {
                    out[beid[i + j]] = __fdividef(__int_as_float(bdx[i + j]),
                                                  segsum[bs[i + j] & 0x1FFFF]);
                }
            }
        }
    }
}

extern "C" void kernel_launch(void* const* d_in, const int* in_sizes, int n_in,
                              void* d_out, int out_size, void* d_ws, size_t ws_size,
                              hipStream_t stream) {
    const float* x     = (const float*)d_in[0];
    const float* a     = (const float*)d_in[1];
    const int*   eidx  = (const int*)d_in[2];
    const int*   etype = (const int*)d_in[3];
    const int*   srcs  = eidx;
    const int*   dsts  = eidx + NE;
    float*       out   = (float*)d_out;

    // ws layout (all offsets 16-aligned)
    char* ws = (char*)d_ws;
    __half*   table  = (__half*)(ws);                         //  6,400,000 B
    int*      bs     = (int*)(ws + 6400000);                  //  3,244,032 B
    int*      bdx    = (int*)(ws + 9644032);                  //  3,244,032 B
    int*      beid   = (int*)(ws + 12888064);                 //  3,244,032 B
    float*    segsum = (float*)(ws + 16132096);               //    400,000 B
    unsigned* ctr    = (unsigned*)(ws + 16532096);            //         64 B
    unsigned* scur   = ctr;
    unsigned* bcur   = ctr + 8;

    dim3 blk(256);
    zero_counters<<<dim3(1), dim3(64), 0, stream>>>(ctr);
    pre_scatter<<<dim3(PRE_BLOCKS + SC_BLOCKS), blk, 0, stream>>>(
        x, a, srcs, dsts, etype, table, segsum, scur, bs, bdx, beid);
    edge_ab<<<dim3(1024), blk, 0, stream>>>(scur, bcur, bs, bdx, table, segsum);
    edge_c<<<dim3(1024), blk, 0, stream>>>(scur, bs, bdx, beid, segsum, out);
}

// Round 7
// 78.641 us; speedup vs baseline: 1.2325x; 1.2325x over previous
//
#include <hip/hip_runtime.h>
#include <hip/hip_fp16.h>

#define NN 100000
#define NE 625000
#define ND 128
#define NR 16
#define SLOPE 0.2f
#define PAD 132          // floats per LDS x-row: 128+4 (conflict-free ds_read_b128)
#define NPART (8 * NN)   // 8 per-XCD replicated partial segment sums

// K1: precompute interleaved fp16 table: table[n*32 + o]
//   o in [0,16)  : U_o(n)      = dot(a[o][0:128],    x[n])
//   o in [16,32) : V_{o-16}(n) = dot(a[o-16][128:256], x[n])
// 4 waves/block, 64 nodes; wave q computes outputs q*8..q*8+7 for all 64 nodes
// (A-row address wave-uniform -> scalar K$ loads). x staged coalesced in LDS.
// Also zeroes this block's 512-float slice of the partial-sum arrays.
__global__ __launch_bounds__(256) void precompute_table(
        const float* __restrict__ x, const float* __restrict__ a,
        __half* __restrict__ table, float* __restrict__ part) {
    __shared__ float xs[64 * PAD];          // 33,792 B

    int tid = threadIdx.x;
    int blockBase = blockIdx.x * 64;

    // zero partial arrays: 1563 blocks x 512 floats >= 800,000
    if (tid < 128) {
        int idx = blockIdx.x * 512 + tid * 4;
        if (idx < NPART)
            *(float4*)&part[idx] = make_float4(0.f, 0.f, 0.f, 0.f);
    }

    // stage 64 node rows (32 KB) fully coalesced
#pragma unroll
    for (int i = 0; i < 8; ++i) {
        int f = tid + i * 256;
        int row = f >> 5;
        int col = (f & 31) << 2;
        size_t g = (size_t)blockBase * ND + (size_t)f * 4;
        float4 v = (g < (size_t)NN * ND) ? *(const float4*)&x[g]
                                         : make_float4(0.f, 0.f, 0.f, 0.f);
        *(float4*)&xs[row * PAD + col] = v;
    }
    __syncthreads();

    int q  = __builtin_amdgcn_readfirstlane(tid >> 6);  // wave id, uniform
    int nl = tid & 63;
    int n  = blockBase + nl;
    if (n >= NN) return;

    const float* arow = a + (size_t)((q & 1) * 8) * 256 + (q >> 1) * 128;
    float acc[8];
#pragma unroll
    for (int j = 0; j < 8; ++j) acc[j] = 0.0f;

    const float* xr = &xs[nl * PAD];
    for (int k = 0; k < ND; k += 4) {
        float4 xv = *(const float4*)&xr[k];
#pragma unroll
        for (int j = 0; j < 8; ++j) {
            float4 av = *(const float4*)&arow[(size_t)j * 256 + k];   // s_load
            acc[j] += av.x * xv.x + av.y * xv.y + av.z * xv.z + av.w * xv.w;
        }
    }

    __half2 hv[4];
#pragma unroll
    for (int p = 0; p < 4; ++p)
        hv[p] = __floats2half2_rn(acc[p * 2], acc[p * 2 + 1]);
    *(uint4*)(table + (size_t)n * 32 + q * 8) = *(uint4*)hv;
}

// K2: 4 edges/thread. e = U[src][r] + V[dst][r]; leaky-relu; exp (softmax is
// shift-invariant, |e| < ~12 so no max pass); store ex; accumulate the segment
// sum into THIS XCD's private partial array with WORKGROUP-scope atomics:
// they execute in the local TCC (no sc1 / MALL write-through). Correct because
// each partial array is only ever touched by blocks on its own XCD, and the
// kernel-end release flushes L2 before the reduce kernel reads it.
__global__ __launch_bounds__(256) void edge_ab(
        const int* __restrict__ srcs, const int* __restrict__ dsts,
        const int* __restrict__ etype, const __half* __restrict__ table,
        float* __restrict__ ex_buf, float* __restrict__ part) {
    int xcd;
    asm volatile("s_getreg_b32 %0, hwreg(HW_REG_XCC_ID)" : "=s"(xcd));
    float* mypart = part + (size_t)(xcd & 7) * NN;

    int t = blockIdx.x * blockDim.x + threadIdx.x;
    int e = t * 4;
    if (e >= NE) return;   // NE % 4 == 0 -> no partial tail
    int4 s4 = *(const int4*)&srcs[e];
    int4 d4 = *(const int4*)&dsts[e];
    int4 r4 = *(const int4*)&etype[e];
    int s[4] = {s4.x, s4.y, s4.z, s4.w};
    int d[4] = {d4.x, d4.y, d4.z, d4.w};
    int r[4] = {r4.x, r4.y, r4.z, r4.w};

    float u[4], v[4];
#pragma unroll
    for (int j = 0; j < 4; ++j)
        u[j] = __half2float(table[(size_t)s[j] * 32 + r[j]]);
#pragma unroll
    for (int j = 0; j < 4; ++j)
        v[j] = __half2float(table[(size_t)d[j] * 32 + 16 + r[j]]);

    float ex[4];
#pragma unroll
    for (int j = 0; j < 4; ++j) {
        float av = u[j] + v[j];
        av = (av >= 0.f) ? av : SLOPE * av;
        ex[j] = __expf(av);
    }
    float4 exv; exv.x = ex[0]; exv.y = ex[1]; exv.z = ex[2]; exv.w = ex[3];
    *(float4*)&ex_buf[e] = exv;
#pragma unroll
    for (int j = 0; j < 4; ++j)
        __hip_atomic_fetch_add(&mypart[s[j]], ex[j],
                               __ATOMIC_RELAXED, __HIP_MEMORY_SCOPE_WORKGROUP);
}

// K3: segsum[n] = sum over the 8 per-XCD partials
__global__ __launch_bounds__(256) void reduce_part(
        const float* __restrict__ part, float* __restrict__ segsum) {
    int n4 = (blockIdx.x * blockDim.x + threadIdx.x) * 4;
    if (n4 >= NN) return;      // NN % 4 == 0
    float4 s = *(const float4*)&part[n4];
#pragma unroll
    for (int g = 1; g < 8; ++g) {
        float4 p = *(const float4*)&part[(size_t)g * NN + n4];
        s.x += p.x; s.y += p.y; s.z += p.z; s.w += p.w;
    }
    *(float4*)&segsum[n4] = s;
}

// K4: alpha = ex / segsum[src], 4 edges/thread (segsum = 400 KB, cache-hot)
__global__ __launch_bounds__(256) void edge_c(
        const int* __restrict__ srcs, const float* __restrict__ ex_buf,
        const float* __restrict__ segsum, float* __restrict__ out) {
    int t = blockIdx.x * blockDim.x + threadIdx.x;
    int e = t * 4;
    if (e >= NE) return;
    int4 s4 = *(const int4*)&srcs[e];
    float4 ex = *(const float4*)&ex_buf[e];
    float ss0 = segsum[s4.x];
    float ss1 = segsum[s4.y];
    float ss2 = segsum[s4.z];
    float ss3 = segsum[s4.w];
    float4 o;
    o.x = __fdividef(ex.x, ss0);
    o.y = __fdividef(ex.y, ss1);
    o.z = __fdividef(ex.z, ss2);
    o.w = __fdividef(ex.w, ss3);
    *(float4*)&out[e] = o;
}

extern "C" void kernel_launch(void* const* d_in, const int* in_sizes, int n_in,
                              void* d_out, int out_size, void* d_ws, size_t ws_size,
                              hipStream_t stream) {
    const float* x     = (const float*)d_in[0];           // [NN, 128]
    const float* a     = (const float*)d_in[1];           // [16, 256]
    const int*   eidx  = (const int*)d_in[2];             // [2, NE]
    const int*   etype = (const int*)d_in[3];             // [NE]
    const int*   srcs  = eidx;
    const int*   dsts  = eidx + NE;
    float*       out   = (float*)d_out;

    // ws layout (16B-aligned)
    char* ws = (char*)d_ws;
    __half* table  = (__half*)(ws);                        //  6,400,000 B
    float*  ex_buf = (float*)(ws + 6400000);               //  2,500,000 B
    float*  part   = (float*)(ws + 8900000);               //  3,200,000 B
    float*  segsum = (float*)(ws + 12100000);              //    400,000 B

    dim3 blk(256);
    dim3 pgrid((NN + 63) / 64);                            // 1563
    dim3 egrid((NE / 4 + 255) / 256);                      // 611
    dim3 rgrid((NN / 4 + 255) / 256);                      // 98

    precompute_table<<<pgrid, blk, 0, stream>>>(x, a, table, part);
    edge_ab<<<egrid, blk, 0, stream>>>(srcs, dsts, etype, table, ex_buf, part);
    reduce_part<<<rgrid, blk, 0, stream>>>(part, segsum);
    edge_c<<<egrid, blk, 0, stream>>>(srcs, ex_buf, segsum, out);
}

// Round 8
// 59.186 us; speedup vs baseline: 1.6376x; 1.3287x over previous
//
#include <hip/hip_runtime.h>
#include <hip/hip_fp16.h>

#define NN 100000
#define NE 625000
#define ND 128
#define NR 16
#define SLOPE 0.2f
#define PAD 132            // floats per LDS x-row: 128+4 (conflict-free ds_read_b128)
#define NB 782             // src buckets: ceil(NN/128), 128 nodes each
#define CAP 1280           // slots/bucket; mean 799, +17 sigma
#define MAXE 5             // CAP/256 edges per thread in fused_abc
#define PRE_BLOCKS 1563    // ceil(NN/64)
#define SC_EPB 8192        // edges per scatter block (32/thread)
#define SC_BLOCKS 77       // ceil(NE/SC_EPB)

// Fused kernel, two independent roles by blockIdx:
//  role A (blocks [0,1563)): precompute interleaved fp16 table: table[n*32+o],
//    o<16: U_o(n)=dot(a[o][0:128],x[n]); o>=16: V_{o-16}(n)=dot(a[o-16][128:256],x[n]).
//    One 64 B line per node. 4 waves/block, 64 nodes; wave q computes outputs
//    q*8..q*8+7 (A-row wave-uniform -> scalar K$ loads); x staged in padded LDS.
//  role B (blocks [1563,1640)): bin 8192 edges by (src>>7) into bucket array:
//    bedge[bk*CAP+slot] = { src_local | rel<<7 | dst<<11 , eid }.
//    Two-sweep LDS histogram + one global cursor reservation per bucket.
__global__ __launch_bounds__(256) void pre_scatter(
        const float* __restrict__ x, const float* __restrict__ a,
        const int* __restrict__ srcs, const int* __restrict__ dsts,
        const int* __restrict__ etype,
        __half* __restrict__ table, int2* __restrict__ bedge,
        unsigned* __restrict__ cursor) {
    __shared__ float xs[64 * PAD];          // 33,792 B (role B aliases as hist)
    int tid = threadIdx.x;
    int b = blockIdx.x;

    if (b < PRE_BLOCKS) {
        // ---------------- role A: precompute ----------------
        int blockBase = b * 64;
#pragma unroll
        for (int i = 0; i < 8; ++i) {
            int f = tid + i * 256;
            int row = f >> 5;
            int col = (f & 31) << 2;
            size_t g = (size_t)blockBase * ND + (size_t)f * 4;
            float4 v = (g < (size_t)NN * ND) ? *(const float4*)&x[g]
                                             : make_float4(0.f, 0.f, 0.f, 0.f);
            *(float4*)&xs[row * PAD + col] = v;
        }
        __syncthreads();

        int q  = __builtin_amdgcn_readfirstlane(tid >> 6);
        int nl = tid & 63;
        int n  = blockBase + nl;
        if (n >= NN) return;

        const float* arow = a + (size_t)((q & 1) * 8) * 256 + (q >> 1) * 128;
        float acc[8];
#pragma unroll
        for (int j = 0; j < 8; ++j) acc[j] = 0.0f;

        const float* xr = &xs[nl * PAD];
        for (int k = 0; k < ND; k += 4) {
            float4 xv = *(const float4*)&xr[k];
#pragma unroll
            for (int j = 0; j < 8; ++j) {
                float4 av = *(const float4*)&arow[(size_t)j * 256 + k];  // s_load
                acc[j] += av.x * xv.x + av.y * xv.y + av.z * xv.z + av.w * xv.w;
            }
        }
        __half2 hv[4];
#pragma unroll
        for (int p = 0; p < 4; ++p)
            hv[p] = __floats2half2_rn(acc[p * 2], acc[p * 2 + 1]);
        *(uint4*)(table + (size_t)n * 32 + q * 8) = *(uint4*)hv;
    } else {
        // ---------------- role B: bucket scatter ----------------
        unsigned* hist = (unsigned*)xs;      // [NB]
        for (int j = tid; j < NB; j += 256) hist[j] = 0u;
        __syncthreads();

        int base = (b - PRE_BLOCKS) * SC_EPB;
        // sweep 1: per-bucket counts
#pragma unroll
        for (int i = 0; i < 8; ++i) {
            int e = base + (i * 256 + tid) * 4;
            if (e < NE) {                    // NE % 4 == 0: whole int4 valid
                int4 s4 = *(const int4*)&srcs[e];
                atomicAdd(&hist[s4.x >> 7], 1u);
                atomicAdd(&hist[s4.y >> 7], 1u);
                atomicAdd(&hist[s4.z >> 7], 1u);
                atomicAdd(&hist[s4.w >> 7], 1u);
            }
        }
        __syncthreads();
        // reserve global ranges; hist[j] becomes this block's running cursor
        for (int j = tid; j < NB; j += 256) {
            unsigned c = hist[j];
            hist[j] = c ? atomicAdd(&cursor[j], c) : 0u;
        }
        __syncthreads();
        // sweep 2: place edges
#pragma unroll
        for (int i = 0; i < 8; ++i) {
            int e = base + (i * 256 + tid) * 4;
            if (e < NE) {
                int4 s4 = *(const int4*)&srcs[e];
                int4 d4 = *(const int4*)&dsts[e];
                int4 r4 = *(const int4*)&etype[e];
                int ss[4] = {s4.x, s4.y, s4.z, s4.w};
                int dd[4] = {d4.x, d4.y, d4.z, d4.w};
                int rr[4] = {r4.x, r4.y, r4.z, r4.w};
#pragma unroll
                for (int j = 0; j < 4; ++j) {
                    int bk = ss[j] >> 7;
                    unsigned slot = atomicAdd(&hist[bk], 1u);
                    if (slot < CAP) {
                        int w0 = (ss[j] & 127) | (rr[j] << 7) | (dd[j] << 11);
                        bedge[(size_t)bk * CAP + slot] = make_int2(w0, e + j);
                    }
                }
            }
        }
    }
}

// One block per src-bucket: every edge with src in [b*128,(b+1)*128) is here.
// Phase 1: gather u (8 KB-local slab) + v (random), ex = exp(lrelu(u+v)),
//          segment-sum in LDS (ds_add_f32) -- NO global atomics anywhere.
// Phase 2: out[eid] = ex / lsum[src_local].
__global__ __launch_bounds__(256) void fused_abc(
        const unsigned* __restrict__ cursor, const int2* __restrict__ bedge,
        const __half* __restrict__ table, float* __restrict__ out) {
    __shared__ float lsum[128];
    int b = blockIdx.x;
    int tid = threadIdx.x;
    if (tid < 128) lsum[tid] = 0.f;
    __syncthreads();

    unsigned count = cursor[b];
    if (count > CAP) count = CAP;
    const int2* bin = bedge + (size_t)b * CAP;

    int2 ed[MAXE];
    float u[MAXE], v[MAXE], ex[MAXE];

    // coalesced bucket reads, 5-deep ILP
#pragma unroll
    for (int k = 0; k < MAXE; ++k) {
        unsigned i = tid + 256u * k;
        if (i < count) ed[k] = bin[i];
    }
    // independent gathers in flight
#pragma unroll
    for (int k = 0; k < MAXE; ++k) {
        unsigned i = tid + 256u * k;
        if (i < count) {
            int w = ed[k].x;
            int sl = w & 127;
            int r  = (w >> 7) & 15;
            int d  = w >> 11;
            u[k] = __half2float(table[(size_t)((b << 7) + sl) * 32 + r]);
            v[k] = __half2float(table[(size_t)d * 32 + 16 + r]);
        }
    }
#pragma unroll
    for (int k = 0; k < MAXE; ++k) {
        unsigned i = tid + 256u * k;
        if (i < count) {
            float av = u[k] + v[k];
            av = (av >= 0.f) ? av : SLOPE * av;
            ex[k] = __expf(av);
            atomicAdd(&lsum[ed[k].x & 127], ex[k]);   // ds_add_f32
        }
    }
    __syncthreads();
#pragma unroll
    for (int k = 0; k < MAXE; ++k) {
        unsigned i = tid + 256u * k;
        if (i < count)
            out[ed[k].y] = __fdividef(ex[k], lsum[ed[k].x & 127]);
    }
}

extern "C" void kernel_launch(void* const* d_in, const int* in_sizes, int n_in,
                              void* d_out, int out_size, void* d_ws, size_t ws_size,
                              hipStream_t stream) {
    const float* x     = (const float*)d_in[0];           // [NN, 128]
    const float* a     = (const float*)d_in[1];           // [16, 256]
    const int*   eidx  = (const int*)d_in[2];             // [2, NE]
    const int*   etype = (const int*)d_in[3];             // [NE]
    const int*   srcs  = eidx;
    const int*   dsts  = eidx + NE;
    float*       out   = (float*)d_out;

    // ws layout (8/16B-aligned)
    char* ws = (char*)d_ws;
    __half*   table  = (__half*)(ws);                      //  6,400,000 B
    int2*     bedge  = (int2*)(ws + 6400000);              //  8,007,680 B (NB*CAP*8)
    unsigned* cursor = (unsigned*)(ws + 14407680);         //      3,128 B

    hipMemsetAsync(cursor, 0, NB * sizeof(unsigned), stream);

    dim3 blk(256);
    pre_scatter<<<dim3(PRE_BLOCKS + SC_BLOCKS), blk, 0, stream>>>(
        x, a, srcs, dsts, etype, table, bedge, cursor);
    fused_abc<<<dim3(NB), blk, 0, stream>>>(cursor, bedge, table, out);
}

// Round 9
// 53.553 us; speedup vs baseline: 1.8099x; 1.1052x over previous
//
#include <hip/hip_runtime.h>
#include <hip/hip_fp16.h>

#define NN 100000
#define NE 625000
#define ND 128
#define NR 16
#define SLOPE 0.2f
#define PAD 132            // floats per LDS x-row: 128+4 (conflict-free ds_read_b128)
#define NB 782             // src buckets: ceil(NN/128), 128 nodes each
#define CAP 1280           // slots/bucket; mean 799, +17 sigma
#define MAXE 5             // CAP/256 edges per thread in fused_abc
#define PRE_BLOCKS 1563    // ceil(NN/64)
#define SC_EPB 8192        // edges per scatter block (32/thread)
#define SC_BLOCKS 77       // ceil(NE/SC_EPB)

__global__ void zero_cursor(unsigned* __restrict__ c) {
    int i = blockIdx.x * 256 + threadIdx.x;
    if (i < NB) c[i] = 0u;
}

// Fused kernel, two independent roles by blockIdx.
//  role B (blocks [0,77)): FIRST so it overlaps role A instead of tailing it.
//    Bin 8192 edges by (src>>7): bedge[bk*CAP+slot] = {src_local|rel<<7|dst<<11, eid}.
//    Two-sweep LDS histogram + one global cursor reservation per bucket per block.
//  role A (blocks [77,1640)): precompute interleaved fp16 table: table[n*32+o],
//    o<16: U_o(n)=dot(a[o][0:128],x[n]); o>=16: V_{o-16}(n)=dot(a[o-16][128:256],x[n]).
//    One 64 B line per node. 4 waves/block, 64 nodes; wave q computes outputs
//    q*8..q*8+7 (A-row wave-uniform -> scalar K$ loads); x staged in padded LDS.
__global__ __launch_bounds__(256) void pre_scatter(
        const float* __restrict__ x, const float* __restrict__ a,
        const int* __restrict__ srcs, const int* __restrict__ dsts,
        const int* __restrict__ etype,
        __half* __restrict__ table, int2* __restrict__ bedge,
        unsigned* __restrict__ cursor) {
    __shared__ float xs[64 * PAD];          // 33,792 B (role B aliases as hist)
    int tid = threadIdx.x;
    int b = blockIdx.x;

    if (b >= SC_BLOCKS) {
        // ---------------- role A: precompute ----------------
        int blockBase = (b - SC_BLOCKS) * 64;
#pragma unroll
        for (int i = 0; i < 8; ++i) {
            int f = tid + i * 256;
            int row = f >> 5;
            int col = (f & 31) << 2;
            size_t g = (size_t)blockBase * ND + (size_t)f * 4;
            float4 v = (g < (size_t)NN * ND) ? *(const float4*)&x[g]
                                             : make_float4(0.f, 0.f, 0.f, 0.f);
            *(float4*)&xs[row * PAD + col] = v;
        }
        __syncthreads();

        int q  = __builtin_amdgcn_readfirstlane(tid >> 6);
        int nl = tid & 63;
        int n  = blockBase + nl;
        if (n >= NN) return;

        const float* arow = a + (size_t)((q & 1) * 8) * 256 + (q >> 1) * 128;
        float acc[8];
#pragma unroll
        for (int j = 0; j < 8; ++j) acc[j] = 0.0f;

        const float* xr = &xs[nl * PAD];
        for (int k = 0; k < ND; k += 4) {
            float4 xv = *(const float4*)&xr[k];
#pragma unroll
            for (int j = 0; j < 8; ++j) {
                float4 av = *(const float4*)&arow[(size_t)j * 256 + k];  // s_load
                acc[j] += av.x * xv.x + av.y * xv.y + av.z * xv.z + av.w * xv.w;
            }
        }
        __half2 hv[4];
#pragma unroll
        for (int p = 0; p < 4; ++p)
            hv[p] = __floats2half2_rn(acc[p * 2], acc[p * 2 + 1]);
        *(uint4*)(table + (size_t)n * 32 + q * 8) = *(uint4*)hv;
    } else {
        // ---------------- role B: bucket scatter ----------------
        unsigned* hist = (unsigned*)xs;      // [NB]
        for (int j = tid; j < NB; j += 256) hist[j] = 0u;
        __syncthreads();

        int base = b * SC_EPB;
        // sweep 1: per-bucket counts
#pragma unroll
        for (int i = 0; i < 8; ++i) {
            int e = base + (i * 256 + tid) * 4;
            if (e < NE) {                    // NE % 4 == 0: whole int4 valid
                int4 s4 = *(const int4*)&srcs[e];
                atomicAdd(&hist[s4.x >> 7], 1u);
                atomicAdd(&hist[s4.y >> 7], 1u);
                atomicAdd(&hist[s4.z >> 7], 1u);
                atomicAdd(&hist[s4.w >> 7], 1u);
            }
        }
        __syncthreads();
        // reserve global ranges; hist[j] becomes this block's running cursor
        for (int j = tid; j < NB; j += 256) {
            unsigned c = hist[j];
            hist[j] = c ? atomicAdd(&cursor[j], c) : 0u;
        }
        __syncthreads();
        // sweep 2: place edges
#pragma unroll
        for (int i = 0; i < 8; ++i) {
            int e = base + (i * 256 + tid) * 4;
            if (e < NE) {
                int4 s4 = *(const int4*)&srcs[e];
                int4 d4 = *(const int4*)&dsts[e];
                int4 r4 = *(const int4*)&etype[e];
                int ss[4] = {s4.x, s4.y, s4.z, s4.w};
                int dd[4] = {d4.x, d4.y, d4.z, d4.w};
                int rr[4] = {r4.x, r4.y, r4.z, r4.w};
#pragma unroll
                for (int j = 0; j < 4; ++j) {
                    int bk = ss[j] >> 7;
                    unsigned slot = atomicAdd(&hist[bk], 1u);
                    if (slot < CAP) {
                        int w0 = (ss[j] & 127) | (rr[j] << 7) | (dd[j] << 11);
                        bedge[(size_t)bk * CAP + slot] = make_int2(w0, e + j);
                    }
                }
            }
        }
    }
}

// One block per src-bucket: every edge with src in [b*128,(b+1)*128) is here.
// Phase 1: gather u (8 KB-local slab) + v (random), ex = exp(lrelu(u+v))
//          (softmax shift-invariant, |e|<~12 -> no max pass),
//          segment-sum in LDS (ds_add_f32) -- NO global atomics anywhere.
// Phase 2: out[eid] = ex / lsum[src_local].
__global__ __launch_bounds__(256) void fused_abc(
        const unsigned* __restrict__ cursor, const int2* __restrict__ bedge,
        const __half* __restrict__ table, float* __restrict__ out) {
    __shared__ float lsum[128];
    int b = blockIdx.x;
    int tid = threadIdx.x;
    if (tid < 128) lsum[tid] = 0.f;
    __syncthreads();

    unsigned count = cursor[b];
    if (count > CAP) count = CAP;
    const int2* bin = bedge + (size_t)b * CAP;

    int2 ed[MAXE];
    float u[MAXE], v[MAXE], ex[MAXE];

    // coalesced bucket reads, 5-deep ILP
#pragma unroll
    for (int k = 0; k < MAXE; ++k) {
        unsigned i = tid + 256u * k;
        if (i < count) ed[k] = bin[i];
    }
    // independent gathers in flight
#pragma unroll
    for (int k = 0; k < MAXE; ++k) {
        unsigned i = tid + 256u * k;
        if (i < count) {
            int w = ed[k].x;
            int sl = w & 127;
            int r  = (w >> 7) & 15;
            int d  = w >> 11;
            u[k] = __half2float(table[(size_t)((b << 7) + sl) * 32 + r]);
            v[k] = __half2float(table[(size_t)d * 32 + 16 + r]);
        }
    }
#pragma unroll
    for (int k = 0; k < MAXE; ++k) {
        unsigned i = tid + 256u * k;
        if (i < count) {
            float av = u[k] + v[k];
            av = (av >= 0.f) ? av : SLOPE * av;
            ex[k] = __expf(av);
            atomicAdd(&lsum[ed[k].x & 127], ex[k]);   // ds_add_f32
        }
    }
    __syncthreads();
#pragma unroll
    for (int k = 0; k < MAXE; ++k) {
        unsigned i = tid + 256u * k;
        if (i < count)
            out[ed[k].y] = __fdividef(ex[k], lsum[ed[k].x & 127]);
    }
}

extern "C" void kernel_launch(void* const* d_in, const int* in_sizes, int n_in,
                              void* d_out, int out_size, void* d_ws, size_t ws_size,
                              hipStream_t stream) {
    const float* x     = (const float*)d_in[0];           // [NN, 128]
    const float* a     = (const float*)d_in[1];           // [16, 256]
    const int*   eidx  = (const int*)d_in[2];             // [2, NE]
    const int*   etype = (const int*)d_in[3];             // [NE]
    const int*   srcs  = eidx;
    const int*   dsts  = eidx + NE;
    float*       out   = (float*)d_out;

    // ws layout (8/16B-aligned)
    char* ws = (char*)d_ws;
    __half*   table  = (__half*)(ws);                      //  6,400,000 B
    int2*     bedge  = (int2*)(ws + 6400000);              //  8,007,680 B (NB*CAP*8)
    unsigned* cursor = (unsigned*)(ws + 14407680);         //      3,128 B

    dim3 blk(256);
    zero_cursor<<<dim3(4), blk, 0, stream>>>(cursor);
    pre_scatter<<<dim3(PRE_BLOCKS + SC_BLOCKS), blk, 0, stream>>>(
        x, a, srcs, dsts, etype, table, bedge, cursor);
    fused_abc<<<dim3(NB), blk, 0, stream>>>(cursor, bedge, table, out);
}

// Round 10
// 45.875 us; speedup vs baseline: 2.1128x; 1.1674x over previous
//
#include <hip/hip_runtime.h>
#include <hip/hip_fp16.h>

#define NN 100000
#define NE 625000
#define ND 128
#define NR 16
#define SLOPE 0.2f
#define NB 782             // src buckets: ceil(NN/128), 128 nodes each
#define CAP 1280           // slots/bucket; mean 799, +17 sigma
#define MAXE 5             // CAP/256 edges per thread in fused_abc
#define PRE_BLOCKS 1563    // ceil(NN/64): 64 nodes per MFMA block
#define SC_EPB 4096        // edges per scatter block (16/thread)
#define SC_BLOCKS 153      // ceil(NE/SC_EPB)
#define LSTR 136           // LDS row stride in bf16 elems (128 + 8: 272 B, 16B-aligned)

using s16x8 = __attribute__((ext_vector_type(8))) short;
using f32x4 = __attribute__((ext_vector_type(4))) float;

__global__ void zero_cursor(unsigned* __restrict__ c) {
    int i = blockIdx.x * 256 + threadIdx.x;
    if (i < NB) c[i] = 0u;
}

// split float into bf16 hi (truncate) + bf16 lo (truncate of remainder):
// x ~= hi + lo with ~16 mantissa bits retained
__device__ __forceinline__ void bf_split(float x, unsigned short& h, unsigned short& l) {
    unsigned u = __float_as_uint(x);
    h = (unsigned short)(u >> 16);
    float hf = __uint_as_float(u & 0xFFFF0000u);
    l = (unsigned short)(__float_as_uint(x - hf) >> 16);
}

// Fused kernel, two roles by blockIdx (role B FIRST so it overlaps role A):
//  role B (blocks [0,153)): bin 4096 edges by (src>>7):
//    bedge[bk*CAP+slot] = {src_local|rel<<7|dst<<11, eid}; two-sweep LDS histogram
//    + one global cursor reservation per bucket per block.
//  role A (blocks [153,1716)): MFMA precompute of interleaved fp16 table:
//    table[n*32+o]: o<16: dot(a[o][0:128],x[n]); o>=16: dot(a[o-16][128:256],x[n]).
//    X,W split into bf16 hi/lo; D = Xh*Wh + Xl*Wh + Xh*Wl (3-term, ~fp32 accuracy).
//    4 waves; wave w owns a 16-node M-tile, computes 16x32 output via
//    2 N-tiles x 4 K-steps x 3 terms = 24 mfma_f32_16x16x32_bf16.
__global__ __launch_bounds__(256) void pre_scatter(
        const float* __restrict__ x, const float* __restrict__ a,
        const int* __restrict__ srcs, const int* __restrict__ dsts,
        const int* __restrict__ etype,
        __half* __restrict__ table, int2* __restrict__ bedge,
        unsigned* __restrict__ cursor) {
    __shared__ __align__(16) unsigned short smem[4 * 16 + 64 * LSTR * 2 + 32 * LSTR * 2];
    int tid = threadIdx.x;
    int b = blockIdx.x;

    if (b >= SC_BLOCKS) {
        // ---------------- role A: MFMA precompute ----------------
        unsigned short* Xh = smem;                    // 64 x LSTR
        unsigned short* Xl = Xh + 64 * LSTR;
        unsigned short* Wh = Xl + 64 * LSTR;          // 32 x LSTR, rows = outputs o
        unsigned short* Wl = Wh + 32 * LSTR;
        int nb = (b - SC_BLOCKS) * 64;

        // stage X: 64 rows x 128 floats, coalesced, split hi/lo
#pragma unroll
        for (int i = 0; i < 8; ++i) {
            int f = tid + i * 256;                    // float4 slot [0,2048)
            int row = f >> 5;
            int c4 = (f & 31) << 2;
            size_t g = (size_t)nb * ND + (size_t)f * 4;
            float4 v = (g < (size_t)NN * ND) ? *(const float4*)&x[g]
                                             : make_float4(0.f, 0.f, 0.f, 0.f);
            unsigned short h0, l0, h1, l1, h2, l2, h3, l3;
            bf_split(v.x, h0, l0); bf_split(v.y, h1, l1);
            bf_split(v.z, h2, l2); bf_split(v.w, h3, l3);
            *(uint2*)&Xh[row * LSTR + c4] =
                make_uint2((unsigned)h0 | ((unsigned)h1 << 16),
                           (unsigned)h2 | ((unsigned)h3 << 16));
            *(uint2*)&Xl[row * LSTR + c4] =
                make_uint2((unsigned)l0 | ((unsigned)l1 << 16),
                           (unsigned)l2 | ((unsigned)l3 << 16));
        }
        // stage W: Wfull[o][k] = a[o&15][(o>>4)*128 + k], 1024 float4s
#pragma unroll
        for (int i = 0; i < 4; ++i) {
            int f = tid + i * 256;                    // [0,1024)
            int row = f >> 6;                         // a-row 0..15
            int c4 = f & 63;
            int o = row + ((c4 >> 5) << 4);
            int k = (c4 & 31) << 2;
            float4 v = *(const float4*)&a[(size_t)row * 256 + (size_t)c4 * 4];
            unsigned short h0, l0, h1, l1, h2, l2, h3, l3;
            bf_split(v.x, h0, l0); bf_split(v.y, h1, l1);
            bf_split(v.z, h2, l2); bf_split(v.w, h3, l3);
            *(uint2*)&Wh[o * LSTR + k] =
                make_uint2((unsigned)h0 | ((unsigned)h1 << 16),
                           (unsigned)h2 | ((unsigned)h3 << 16));
            *(uint2*)&Wl[o * LSTR + k] =
                make_uint2((unsigned)l0 | ((unsigned)l1 << 16),
                           (unsigned)l2 | ((unsigned)l3 << 16));
        }
        __syncthreads();

        int w = tid >> 6;          // wave id = M-tile
        int lane = tid & 63;
        int r16 = lane & 15;       // A row within tile / B col within tile
        int q = lane >> 4;         // k-octet selector

        f32x4 acc0 = {0.f, 0.f, 0.f, 0.f};
        f32x4 acc1 = {0.f, 0.f, 0.f, 0.f};
        const unsigned short* xh = &Xh[(w * 16 + r16) * LSTR + q * 8];
        const unsigned short* xl = &Xl[(w * 16 + r16) * LSTR + q * 8];
        const unsigned short* w0h = &Wh[r16 * LSTR + q * 8];          // N-tile 0
        const unsigned short* w0l = &Wl[r16 * LSTR + q * 8];
        const unsigned short* w1h = &Wh[(16 + r16) * LSTR + q * 8];   // N-tile 1
        const unsigned short* w1l = &Wl[(16 + r16) * LSTR + q * 8];
#pragma unroll
        for (int ks = 0; ks < 4; ++ks) {
            s16x8 ah = *(const s16x8*)&xh[ks * 32];
            s16x8 al = *(const s16x8*)&xl[ks * 32];
            s16x8 bh0 = *(const s16x8*)&w0h[ks * 32];
            s16x8 bl0 = *(const s16x8*)&w0l[ks * 32];
            s16x8 bh1 = *(const s16x8*)&w1h[ks * 32];
            s16x8 bl1 = *(const s16x8*)&w1l[ks * 32];
            acc0 = __builtin_amdgcn_mfma_f32_16x16x32_bf16(ah, bh0, acc0, 0, 0, 0);
            acc0 = __builtin_amdgcn_mfma_f32_16x16x32_bf16(al, bh0, acc0, 0, 0, 0);
            acc0 = __builtin_amdgcn_mfma_f32_16x16x32_bf16(ah, bl0, acc0, 0, 0, 0);
            acc1 = __builtin_amdgcn_mfma_f32_16x16x32_bf16(ah, bh1, acc1, 0, 0, 0);
            acc1 = __builtin_amdgcn_mfma_f32_16x16x32_bf16(al, bh1, acc1, 0, 0, 0);
            acc1 = __builtin_amdgcn_mfma_f32_16x16x32_bf16(ah, bl1, acc1, 0, 0, 0);
        }
        // D layout: col = lane&15, row = (lane>>4)*4 + reg
        int nrow = nb + w * 16 + q * 4;
#pragma unroll
        for (int r = 0; r < 4; ++r) {
            int n = nrow + r;
            if (n < NN) {
                table[(size_t)n * 32 + r16]      = __float2half_rn(acc0[r]);
                table[(size_t)n * 32 + 16 + r16] = __float2half_rn(acc1[r]);
            }
        }
    } else {
        // ---------------- role B: bucket scatter ----------------
        unsigned* hist = (unsigned*)smem;      // [NB] = 3128 B
        for (int j = tid; j < NB; j += 256) hist[j] = 0u;
        __syncthreads();

        int base = b * SC_EPB;
        // sweep 1: per-bucket counts
#pragma unroll
        for (int i = 0; i < 4; ++i) {
            int e = base + (i * 256 + tid) * 4;
            if (e < NE) {                      // NE % 4 == 0: whole int4 valid
                int4 s4 = *(const int4*)&srcs[e];
                atomicAdd(&hist[s4.x >> 7], 1u);
                atomicAdd(&hist[s4.y >> 7], 1u);
                atomicAdd(&hist[s4.z >> 7], 1u);
                atomicAdd(&hist[s4.w >> 7], 1u);
            }
        }
        __syncthreads();
        for (int j = tid; j < NB; j += 256) {
            unsigned c = hist[j];
            hist[j] = c ? atomicAdd(&cursor[j], c) : 0u;
        }
        __syncthreads();
        // sweep 2: place edges
#pragma unroll
        for (int i = 0; i < 4; ++i) {
            int e = base + (i * 256 + tid) * 4;
            if (e < NE) {
                int4 s4 = *(const int4*)&srcs[e];
                int4 d4 = *(const int4*)&dsts[e];
                int4 r4 = *(const int4*)&etype[e];
                int ss[4] = {s4.x, s4.y, s4.z, s4.w};
                int dd[4] = {d4.x, d4.y, d4.z, d4.w};
                int rr[4] = {r4.x, r4.y, r4.z, r4.w};
#pragma unroll
                for (int j = 0; j < 4; ++j) {
                    int bk = ss[j] >> 7;
                    unsigned slot = atomicAdd(&hist[bk], 1u);
                    if (slot < CAP) {
                        int w0 = (ss[j] & 127) | (rr[j] << 7) | (dd[j] << 11);
                        bedge[(size_t)bk * CAP + slot] = make_int2(w0, e + j);
                    }
                }
            }
        }
    }
}

// One block per src-bucket: every edge with src in [b*128,(b+1)*128) is here.
// Phase 1: gather u (8 KB-local slab) + v (random), ex = exp(lrelu(u+v))
//          (softmax shift-invariant, |e|<~12 -> no max pass),
//          segment-sum in LDS (ds_add_f32) -- NO global atomics anywhere.
// Phase 2: out[eid] = ex / lsum[src_local].
__global__ __launch_bounds__(256) void fused_abc(
        const unsigned* __restrict__ cursor, const int2* __restrict__ bedge,
        const __half* __restrict__ table, float* __restrict__ out) {
    __shared__ float lsum[128];
    int b = blockIdx.x;
    int tid = threadIdx.x;
    if (tid < 128) lsum[tid] = 0.f;
    __syncthreads();

    unsigned count = cursor[b];
    if (count > CAP) count = CAP;
    const int2* bin = bedge + (size_t)b * CAP;

    int2 ed[MAXE];
    float u[MAXE], v[MAXE], ex[MAXE];

#pragma unroll
    for (int k = 0; k < MAXE; ++k) {
        unsigned i = tid + 256u * k;
        if (i < count) ed[k] = bin[i];
    }
#pragma unroll
    for (int k = 0; k < MAXE; ++k) {
        unsigned i = tid + 256u * k;
        if (i < count) {
            int w = ed[k].x;
            int sl = w & 127;
            int r  = (w >> 7) & 15;
            int d  = w >> 11;
            u[k] = __half2float(table[(size_t)((b << 7) + sl) * 32 + r]);
            v[k] = __half2float(table[(size_t)d * 32 + 16 + r]);
        }
    }
#pragma unroll
    for (int k = 0; k < MAXE; ++k) {
        unsigned i = tid + 256u * k;
        if (i < count) {
            float av = u[k] + v[k];
            av = (av >= 0.f) ? av : SLOPE * av;
            ex[k] = __expf(av);
            atomicAdd(&lsum[ed[k].x & 127], ex[k]);   // ds_add_f32
        }
    }
    __syncthreads();
#pragma unroll
    for (int k = 0; k < MAXE; ++k) {
        unsigned i = tid + 256u * k;
        if (i < count)
            out[ed[k].y] = __fdividef(ex[k], lsum[ed[k].x & 127]);
    }
}

extern "C" void kernel_launch(void* const* d_in, const int* in_sizes, int n_in,
                              void* d_out, int out_size, void* d_ws, size_t ws_size,
                              hipStream_t stream) {
    const float* x     = (const float*)d_in[0];           // [NN, 128]
    const float* a     = (const float*)d_in[1];           // [16, 256]
    const int*   eidx  = (const int*)d_in[2];             // [2, NE]
    const int*   etype = (const int*)d_in[3];             // [NE]
    const int*   srcs  = eidx;
    const int*   dsts  = eidx + NE;
    float*       out   = (float*)d_out;

    // ws layout (8/16B-aligned)
    char* ws = (char*)d_ws;
    __half*   table  = (__half*)(ws);                      //  6,400,000 B
    int2*     bedge  = (int2*)(ws + 6400000);              //  8,007,680 B (NB*CAP*8)
    unsigned* cursor = (unsigned*)(ws + 14407680);         //      3,128 B

    dim3 blk(256);
    zero_cursor<<<dim3(4), blk, 0, stream>>>(cursor);
    pre_scatter<<<dim3(PRE_BLOCKS + SC_BLOCKS), blk, 0, stream>>>(
        x, a, srcs, dsts, etype, table, bedge, cursor);
    fused_abc<<<dim3(NB), blk, 0, stream>>>(cursor, bedge, table, out);
}

// Round 11
// 43.834 us; speedup vs baseline: 2.2112x; 1.0466x over previous
//
#include <hip/hip_runtime.h>
#include <hip/hip_fp16.h>

#define NN 100000
#define NE 625000
#define ND 128
#define NR 16
#define SLOPE 0.2f
#define NB 782             // src buckets: ceil(NN/128), 128 nodes each
#define CAP 1280           // slots/bucket; mean 799, +17 sigma
#define MAXE 5             // CAP/256 edges per thread in fused_abc
#define PRE_BLOCKS 1563    // ceil(NN/64): 64 nodes per MFMA block
#define SC_EPB 4096        // edges per scatter block (16/thread)
#define SC_BLOCKS 153      // ceil(NE/SC_EPB)
#define LSTR 136           // LDS W row stride in bf16 elems (128+8: 272 B, 16B-aligned)

using s16x8 = __attribute__((ext_vector_type(8))) short;
using f32x4 = __attribute__((ext_vector_type(4))) float;

__global__ void zero_cursor(unsigned* __restrict__ c) {
    int i = blockIdx.x * 256 + threadIdx.x;
    if (i < NB) c[i] = 0u;
}

// split float into bf16 hi (truncate) + bf16 lo (truncate of remainder):
// x ~= hi + lo with ~16 mantissa bits retained
__device__ __forceinline__ void bf_split(float x, unsigned short& h, unsigned short& l) {
    unsigned u = __float_as_uint(x);
    h = (unsigned short)(u >> 16);
    float hf = __uint_as_float(u & 0xFFFF0000u);
    l = (unsigned short)(__float_as_uint(x - hf) >> 16);
}

// Fused kernel, two roles by blockIdx (role B FIRST so it overlaps role A):
//  role B (blocks [0,153)): bin 4096 edges by (src>>7):
//    bedge[bk*CAP+slot] = {src_local|rel<<7|dst<<11, eid}; two-sweep LDS histogram
//    + one global cursor reservation per bucket per block.
//  role A (blocks [153,1716)): MFMA precompute of interleaved fp16 table:
//    table[n*32+o]: o<16: dot(a[o][0:128],x[n]); o>=16: dot(a[o-16][128:256],x[n]).
//    X,W split into bf16 hi/lo; D = Xh*Wh + Xl*Wh + Xh*Wl (3-term, ~fp32 accuracy).
//    A-fragments loaded DIRECTLY global->reg (X rows are wave-private; lane l
//    needs x[row=l&15][k=(l>>4)*8+j] = two contiguous float4s per K-step ->
//    dense 128 B/row, coalesced). Only W (shared) is staged in LDS (17.4 KB).
__global__ __launch_bounds__(256) void pre_scatter(
        const float* __restrict__ x, const float* __restrict__ a,
        const int* __restrict__ srcs, const int* __restrict__ dsts,
        const int* __restrict__ etype,
        __half* __restrict__ table, int2* __restrict__ bedge,
        unsigned* __restrict__ cursor) {
    __shared__ __align__(16) unsigned short smem[2 * 32 * LSTR]; // Wh|Wl, 17,408 B
    int tid = threadIdx.x;
    int b = blockIdx.x;

    if (b >= SC_BLOCKS) {
        // ---------------- role A: MFMA precompute ----------------
        unsigned short* Wh = smem;                    // 32 x LSTR, rows = outputs o
        unsigned short* Wl = Wh + 32 * LSTR;
        int nb = (b - SC_BLOCKS) * 64;

        // stage W: Wfull[o][k] = a[o&15][(o>>4)*128 + k], 1024 float4s, hi/lo split
#pragma unroll
        for (int i = 0; i < 4; ++i) {
            int f = tid + i * 256;                    // [0,1024)
            int row = f >> 6;                         // a-row 0..15
            int c4 = f & 63;
            int o = row + ((c4 >> 5) << 4);
            int k = (c4 & 31) << 2;
            float4 v = *(const float4*)&a[(size_t)row * 256 + (size_t)c4 * 4];
            unsigned short h0, l0, h1, l1, h2, l2, h3, l3;
            bf_split(v.x, h0, l0); bf_split(v.y, h1, l1);
            bf_split(v.z, h2, l2); bf_split(v.w, h3, l3);
            *(uint2*)&Wh[o * LSTR + k] =
                make_uint2((unsigned)h0 | ((unsigned)h1 << 16),
                           (unsigned)h2 | ((unsigned)h3 << 16));
            *(uint2*)&Wl[o * LSTR + k] =
                make_uint2((unsigned)l0 | ((unsigned)l1 << 16),
                           (unsigned)l2 | ((unsigned)l3 << 16));
        }
        __syncthreads();

        int w = tid >> 6;          // wave id = M-tile
        int lane = tid & 63;
        int r16 = lane & 15;       // A row within tile / B col within tile
        int q = lane >> 4;         // k-octet selector

        int n = nb + w * 16 + r16;
        bool vld = n < NN;
        const float* xrow = x + (size_t)(vld ? n : 0) * ND + q * 8;

        f32x4 acc0 = {0.f, 0.f, 0.f, 0.f};
        f32x4 acc1 = {0.f, 0.f, 0.f, 0.f};
        const unsigned short* w0h = &Wh[r16 * LSTR + q * 8];          // N-tile 0
        const unsigned short* w0l = &Wl[r16 * LSTR + q * 8];
        const unsigned short* w1h = &Wh[(16 + r16) * LSTR + q * 8];   // N-tile 1
        const unsigned short* w1l = &Wl[(16 + r16) * LSTR + q * 8];
#pragma unroll
        for (int ks = 0; ks < 4; ++ks) {
            float4 v0 = vld ? *(const float4*)&xrow[ks * 32]
                            : make_float4(0.f, 0.f, 0.f, 0.f);
            float4 v1 = vld ? *(const float4*)&xrow[ks * 32 + 4]
                            : make_float4(0.f, 0.f, 0.f, 0.f);
            s16x8 ah, al;
            unsigned short h, lo;
            bf_split(v0.x, h, lo); ah[0] = (short)h; al[0] = (short)lo;
            bf_split(v0.y, h, lo); ah[1] = (short)h; al[1] = (short)lo;
            bf_split(v0.z, h, lo); ah[2] = (short)h; al[2] = (short)lo;
            bf_split(v0.w, h, lo); ah[3] = (short)h; al[3] = (short)lo;
            bf_split(v1.x, h, lo); ah[4] = (short)h; al[4] = (short)lo;
            bf_split(v1.y, h, lo); ah[5] = (short)h; al[5] = (short)lo;
            bf_split(v1.z, h, lo); ah[6] = (short)h; al[6] = (short)lo;
            bf_split(v1.w, h, lo); ah[7] = (short)h; al[7] = (short)lo;

            s16x8 bh0 = *(const s16x8*)&w0h[ks * 32];
            s16x8 bl0 = *(const s16x8*)&w0l[ks * 32];
            s16x8 bh1 = *(const s16x8*)&w1h[ks * 32];
            s16x8 bl1 = *(const s16x8*)&w1l[ks * 32];
            acc0 = __builtin_amdgcn_mfma_f32_16x16x32_bf16(ah, bh0, acc0, 0, 0, 0);
            acc0 = __builtin_amdgcn_mfma_f32_16x16x32_bf16(al, bh0, acc0, 0, 0, 0);
            acc0 = __builtin_amdgcn_mfma_f32_16x16x32_bf16(ah, bl0, acc0, 0, 0, 0);
            acc1 = __builtin_amdgcn_mfma_f32_16x16x32_bf16(ah, bh1, acc1, 0, 0, 0);
            acc1 = __builtin_amdgcn_mfma_f32_16x16x32_bf16(al, bh1, acc1, 0, 0, 0);
            acc1 = __builtin_amdgcn_mfma_f32_16x16x32_bf16(ah, bl1, acc1, 0, 0, 0);
        }
        // D layout: col = lane&15, row = (lane>>4)*4 + reg
        int nrow = nb + w * 16 + q * 4;
#pragma unroll
        for (int r = 0; r < 4; ++r) {
            int nn = nrow + r;
            if (nn < NN) {
                table[(size_t)nn * 32 + r16]      = __float2half_rn(acc0[r]);
                table[(size_t)nn * 32 + 16 + r16] = __float2half_rn(acc1[r]);
            }
        }
    } else {
        // ---------------- role B: bucket scatter ----------------
        unsigned* hist = (unsigned*)smem;      // [NB] = 3128 B (fits in W area)
        for (int j = tid; j < NB; j += 256) hist[j] = 0u;
        __syncthreads();

        int base = b * SC_EPB;
        // sweep 1: per-bucket counts
#pragma unroll
        for (int i = 0; i < 4; ++i) {
            int e = base + (i * 256 + tid) * 4;
            if (e < NE) {                      // NE % 4 == 0: whole int4 valid
                int4 s4 = *(const int4*)&srcs[e];
                atomicAdd(&hist[s4.x >> 7], 1u);
                atomicAdd(&hist[s4.y >> 7], 1u);
                atomicAdd(&hist[s4.z >> 7], 1u);
                atomicAdd(&hist[s4.w >> 7], 1u);
            }
        }
        __syncthreads();
        for (int j = tid; j < NB; j += 256) {
            unsigned c = hist[j];
            hist[j] = c ? atomicAdd(&cursor[j], c) : 0u;
        }
        __syncthreads();
        // sweep 2: place edges
#pragma unroll
        for (int i = 0; i < 4; ++i) {
            int e = base + (i * 256 + tid) * 4;
            if (e < NE) {
                int4 s4 = *(const int4*)&srcs[e];
                int4 d4 = *(const int4*)&dsts[e];
                int4 r4 = *(const int4*)&etype[e];
                int ss[4] = {s4.x, s4.y, s4.z, s4.w};
                int dd[4] = {d4.x, d4.y, d4.z, d4.w};
                int rr[4] = {r4.x, r4.y, r4.z, r4.w};
#pragma unroll
                for (int j = 0; j < 4; ++j) {
                    int bk = ss[j] >> 7;
                    unsigned slot = atomicAdd(&hist[bk], 1u);
                    if (slot < CAP) {
                        int w0 = (ss[j] & 127) | (rr[j] << 7) | (dd[j] << 11);
                        bedge[(size_t)bk * CAP + slot] = make_int2(w0, e + j);
                    }
                }
            }
        }
    }
}

// One block per src-bucket: every edge with src in [b*128,(b+1)*128) is here.
// Phase 1: gather u (8 KB-local slab) + v (random), ex = exp(lrelu(u+v))
//          (softmax shift-invariant, |e|<~12 -> no max pass),
//          segment-sum in LDS (ds_add_f32) -- NO global atomics anywhere.
// Phase 2: out[eid] = ex / lsum[src_local].
__global__ __launch_bounds__(256) void fused_abc(
        const unsigned* __restrict__ cursor, const int2* __restrict__ bedge,
        const __half* __restrict__ table, float* __restrict__ out) {
    __shared__ float lsum[128];
    int b = blockIdx.x;
    int tid = threadIdx.x;
    if (tid < 128) lsum[tid] = 0.f;
    __syncthreads();

    unsigned count = cursor[b];
    if (count > CAP) count = CAP;
    const int2* bin = bedge + (size_t)b * CAP;

    int2 ed[MAXE];
    float u[MAXE], v[MAXE], ex[MAXE];

#pragma unroll
    for (int k = 0; k < MAXE; ++k) {
        unsigned i = tid + 256u * k;
        if (i < count) ed[k] = bin[i];
    }
#pragma unroll
    for (int k = 0; k < MAXE; ++k) {
        unsigned i = tid + 256u * k;
        if (i < count) {
            int w = ed[k].x;
            int sl = w & 127;
            int r  = (w >> 7) & 15;
            int d  = w >> 11;
            u[k] = __half2float(table[(size_t)((b << 7) + sl) * 32 + r]);
            v[k] = __half2float(table[(size_t)d * 32 + 16 + r]);
        }
    }
#pragma unroll
    for (int k = 0; k < MAXE; ++k) {
        unsigned i = tid + 256u * k;
        if (i < count) {
            float av = u[k] + v[k];
            av = (av >= 0.f) ? av : SLOPE * av;
            ex[k] = __expf(av);
            atomicAdd(&lsum[ed[k].x & 127], ex[k]);   // ds_add_f32
        }
    }
    __syncthreads();
#pragma unroll
    for (int k = 0; k < MAXE; ++k) {
        unsigned i = tid + 256u * k;
        if (i < count)
            out[ed[k].y] = __fdividef(ex[k], lsum[ed[k].x & 127]);
    }
}

extern "C" void kernel_launch(void* const* d_in, const int* in_sizes, int n_in,
                              void* d_out, int out_size, void* d_ws, size_t ws_size,
                              hipStream_t stream) {
    const float* x     = (const float*)d_in[0];           // [NN, 128]
    const float* a     = (const float*)d_in[1];           // [16, 256]
    const int*   eidx  = (const int*)d_in[2];             // [2, NE]
    const int*   etype = (const int*)d_in[3];             // [NE]
    const int*   srcs  = eidx;
    const int*   dsts  = eidx + NE;
    float*       out   = (float*)d_out;

    // ws layout (8/16B-aligned)
    char* ws = (char*)d_ws;
    __half*   table  = (__half*)(ws);                      //  6,400,000 B
    int2*     bedge  = (int2*)(ws + 6400000);              //  8,007,680 B (NB*CAP*8)
    unsigned* cursor = (unsigned*)(ws + 14407680);         //      3,128 B

    dim3 blk(256);
    zero_cursor<<<dim3(4), blk, 0, stream>>>(cursor);
    pre_scatter<<<dim3(PRE_BLOCKS + SC_BLOCKS), blk, 0, stream>>>(
        x, a, srcs, dsts, etype, table, bedge, cursor);
    fused_abc<<<dim3(NB), blk, 0, stream>>>(cursor, bedge, table, out);
}